// Round 8
// baseline (828.254 us; speedup 1.0000x reference)
//
#include <hip/hip_runtime.h>
#include <hip/hip_bf16.h>
#include <math.h>

// ---------------------------------------------------------------------------
// MjCambrianOptics: depth-invariant PSF (f32 DFT-as-matmul) + f32 SAME conv.
// Correctness-critical bits (R7-validated, DO NOT TOUCH):
//   * mean(depth) = numpy BUFFERED reduce: seed a[0], then sequential
//     += pairwise_sum(8192-chunk) with 128-leaf/8-acc recursion.
//   * ki = fl32(2pi)/fl32(wl) f32 divide; linspace f64-cast; th/ph op order.
// Perf changes R8: f32 transform chain (R1==R3 proved sub-bf16-ulp impact);
// conv: psf via global *uniform* loads (no LDS broadcast), register row
// cache (9 b128/row vs 16), DI=8 -> 1440 blocks, no wasted i-rows.
// ---------------------------------------------------------------------------

constexpr int M   = 255;
constexpr int NP  = M * M;        // 65025
constexpr int RESO = 160;

// ---------------- numpy buffered-reduce pairwise forest (compile-time) ------
constexpr int MAXN = 1100;
struct PWForest {
    int kind[MAXN];
    int off[MAXN], len[MAXN];
    int li[MAXN], ri[MAXN];
    int lvl[MAXN];
    int leafIdx[MAXN];
    int nNode, nLeaf, maxLvl;
    int roots[16], nRoots;
};
constexpr int pwf_build(PWForest& T, int o, int n) {
    if (n <= 128) {
        int id = T.nNode++;
        T.kind[id] = 0; T.off[id] = o; T.len[id] = n;
        T.lvl[id] = 0; T.leafIdx[id] = T.nLeaf++;
        return id;
    }
    int n2 = (n / 2) - ((n / 2) % 8);
    int a = pwf_build(T, o, n2);
    int b = pwf_build(T, o + n2, n - n2);
    int id = T.nNode++;
    T.kind[id] = 1; T.li[id] = a; T.ri[id] = b;
    int l = (T.lvl[a] > T.lvl[b] ? T.lvl[a] : T.lvl[b]) + 1;
    T.lvl[id] = l; if (l > T.maxLvl) T.maxLvl = l;
    return id;
}
constexpr PWForest pwf_make() {
    PWForest T{};
    int pos = 1, rem = NP - 1;            // reduce seeds with a[0]
    while (rem > 0) {
        int c = rem > 8192 ? 8192 : rem;  // nditer buffer = 8192 elements
        T.roots[T.nRoots++] = pwf_build(T, pos, c);
        pos += c; rem -= c;
    }
    return T;
}
constexpr PWForest PW = pwf_make();
static_assert(PW.nNode <= MAXN, "forest overflow");
static_assert(PW.nRoots == 8, "chunk count");

struct PWLeaves { int off[600]; int len[600]; int n; };
constexpr PWLeaves pw_leaves() {
    PWLeaves L{};
    for (int i = 0; i < PW.nNode; ++i)
        if (PW.kind[i] == 0) { L.off[L.n] = PW.off[i]; L.len[L.n] = PW.len[i]; L.n++; }
    return L;
}
constexpr PWLeaves PWL = pw_leaves();
static_assert(PWL.n <= 600, "leaf overflow");

__global__ void k_leaf(const float* __restrict__ depth, float* __restrict__ leafVal) {
    int t = blockIdx.x * 256 + threadIdx.x;
    if (t >= PWL.n) return;
    const float* a = depth + PWL.off[t];
    int n = PWL.len[t];
    float r0 = a[0], r1 = a[1], r2 = a[2], r3 = a[3];
    float r4 = a[4], r5 = a[5], r6 = a[6], r7 = a[7];
    int lim = n - (n % 8);
    int i = 8;
    for (; i < lim; i += 8) {
        r0 += a[i + 0]; r1 += a[i + 1]; r2 += a[i + 2]; r3 += a[i + 3];
        r4 += a[i + 4]; r5 += a[i + 5]; r6 += a[i + 6]; r7 += a[i + 7];
    }
    float res = ((r0 + r1) + (r2 + r3)) + ((r4 + r5) + (r6 + r7));
    for (; i < n; ++i) res += a[i];
    leafVal[t] = res;
}

__global__ void k_comb(const float* __restrict__ depth,
                       const float* __restrict__ leafVal, float* __restrict__ meanp) {
    __shared__ float val[MAXN];
    int tid = threadIdx.x;
    for (int id = tid; id < PW.nNode; id += 256)
        if (PW.kind[id] == 0) val[id] = leafVal[PW.leafIdx[id]];
    __syncthreads();
    for (int l = 1; l <= PW.maxLvl; ++l) {
        for (int id = tid; id < PW.nNode; id += 256)
            if (PW.kind[id] == 1 && PW.lvl[id] == l)
                val[id] = val[PW.li[id]] + val[PW.ri[id]];
        __syncthreads();
    }
    if (tid == 0) {
        float io1 = depth[0];
        for (int r = 0; r < PW.nRoots; ++r)
            io1 = io1 + val[PW.roots[r]];
        meanp[0] = io1 / 65025.0f;
    }
}

// ---------------- DFT matrix W[n,k] = exp(-2*pi*i*n*k/255), f64->f32 --------
__global__ void k_W32(float2* __restrict__ W) {
    int idx = blockIdx.x * 256 + threadIdx.x;
    if (idx >= NP) return;
    int n = idx / M, k = idx % M;
    int m = (n * k) % M;
    double ang = -2.0 * 3.14159265358979323846 * (double)m / 255.0;
    W[idx] = make_float2((float)cos(ang), (float)sin(ang));
}

// ---------------- u2 and H fields: numpy-f32 faithful (unchanged R7) --------
__global__ void k_u2H(const float* __restrict__ meanp,
                      float2* __restrict__ U2, float2* __restrict__ Hb,
                      double xstart, double xstep, double xstop,
                      double fstart, double fstep, double fstop,
                      float ap_f) {
#pragma clang fp contract(off)
    int idx = blockIdx.x * 256 + threadIdx.x;
    if (idx >= 3 * NP) return;
    int c = idx / NP, ij = idx % NP, i = ij / M, j = ij % M;
    const float wls[3] = {6.1e-07f, 5.3e-07f, 4.7e-07f};
    float wl = wls[c];
    float ki = ((float)6.283185307179586) / wl;
    float d  = meanp[0];
    float d2 = d * d;

    float x  = (i == 254) ? (float)xstop : (float)((double)i * xstep + xstart);
    float y  = (j == 254) ? (float)xstop : (float)((double)j * xstep + xstart);
    float fx = (i == 254) ? (float)fstop : (float)((double)i * fstep + fstart);
    float fy = (j == 254) ? (float)fstop : (float)((double)j * fstep + fstart);

    float xx = x * x, yy = y * y;
    float X1Y1 = xx + yy;

    float s  = sqrtf(X1Y1 + d2);
    float th = ki * s;
    float A  = (sqrtf(X1Y1) / ap_f <= 1.0f) ? 1.0f : 0.0f;
    float2 u2v;
    if (A != 0.0f) u2v = make_float2((float)cos((double)th), (float)sin((double)th));
    else           u2v = make_float2(0.0f, 0.0f);

    float a = wl * fx, b = wl * fy;
    float arg = (1.0f - a * a) - b * b;
    float FXY = sqrtf(fmaxf(arg, 0.0f));
    float Hv  = (sqrtf(fx * fx + fy * fy) < (1.0f / wl)) ? 1.0f : 0.0f;
    float kd  = ki * d;
    float ph  = kd * FXY;
    float cph = (float)cos((double)ph), sph = (float)sin((double)ph);
    float2 hv = make_float2(Hv * cph, Hv * sph);

    U2[idx] = u2v;
    Hb[idx] = hv;
}

// ---------------- batched f32 complex GEMM, 32x32 tile, 2x2/thread ----------
__global__ __launch_bounds__(256)
void k_cgemm32(const float2* __restrict__ A, int aBatch,
               const float2* __restrict__ B, int bBatch,
               float2* __restrict__ C,
               int conjA, int conjB, float scale) {
    __shared__ float2 As[32][17];
    __shared__ float2 Bs[16][33];
    int c = blockIdx.z;
    int tx = threadIdx.x & 15, ty = threadIdx.x >> 4;
    int i0 = blockIdx.y * 32, j0 = blockIdx.x * 32;
    const float2* Ab = A + (size_t)c * aBatch;
    const float2* Bb = B + (size_t)c * bBatch;
    float2 a00 = {0,0}, a01 = {0,0}, a10 = {0,0}, a11 = {0,0};

    for (int kt = 0; kt < 16; ++kt) {
        int k0 = kt * 16;
#pragma unroll
        for (int s = 0; s < 2; ++s) {
            int idx = threadIdx.x + s * 256;
            int r = idx >> 4, cc = idx & 15;
            int gi = i0 + r, gk = k0 + cc;
            float2 v = (gi < M && gk < M) ? Ab[gi * M + gk] : make_float2(0.f, 0.f);
            if (conjA) v.y = -v.y;
            As[r][cc] = v;
            int r2 = idx >> 5, c2 = idx & 31;
            int gk2 = k0 + r2, gj = j0 + c2;
            float2 w = (gk2 < M && gj < M) ? Bb[gk2 * M + gj] : make_float2(0.f, 0.f);
            if (conjB) w.y = -w.y;
            Bs[r2][c2] = w;
        }
        __syncthreads();
#pragma unroll
        for (int kk = 0; kk < 16; ++kk) {
            float2 p = As[ty][kk], q = As[ty + 16][kk];
            float2 u = Bs[kk][tx], v = Bs[kk][tx + 16];
            a00.x += p.x * u.x - p.y * u.y;  a00.y += p.x * u.y + p.y * u.x;
            a01.x += p.x * v.x - p.y * v.y;  a01.y += p.x * v.y + p.y * v.x;
            a10.x += q.x * u.x - q.y * u.y;  a10.y += q.x * u.y + q.y * u.x;
            a11.x += q.x * v.x - q.y * v.y;  a11.y += q.x * v.y + q.y * v.x;
        }
        __syncthreads();
    }
    float2* Cb = C + (size_t)c * NP;
    int gi0 = i0 + ty, gi1 = i0 + ty + 16;
    int gj0 = j0 + tx, gj1 = j0 + tx + 16;
    if (gi0 < M && gj0 < M) Cb[gi0 * M + gj0] = make_float2(a00.x * scale, a00.y * scale);
    if (gi0 < M && gj1 < M) Cb[gi0 * M + gj1] = make_float2(a01.x * scale, a01.y * scale);
    if (gi1 < M && gj0 < M) Cb[gi1 * M + gj0] = make_float2(a10.x * scale, a10.y * scale);
    if (gi1 < M && gj1 < M) Cb[gi1 * M + gj1] = make_float2(a11.x * scale, a11.y * scale);
}

// ---------------- P = FH .* FU (f32) ----------------
__global__ void k_pmul(const float2* __restrict__ FH, const float2* __restrict__ FU,
                       float2* __restrict__ P) {
    int idx = blockIdx.x * 256 + threadIdx.x;
    if (idx >= 3 * NP) return;
    float2 a = FH[idx], b = FU[idx];
    P[idx] = make_float2(a.x * b.x - a.y * b.y, a.x * b.y + a.y * b.x);
}

// ---------------- S = sum u3^2 (f64 accumulate over f32 u3) ----------------
__global__ void k_sred(const float2* __restrict__ U3, double2* __restrict__ spart) {
    __shared__ double sx[256], sy[256];
    int t = threadIdx.x;
    double ax = 0.0, ay = 0.0;
    for (int i = blockIdx.x * 256 + t; i < 3 * NP; i += 64 * 256) {
        double zx = (double)U3[i].x, zy = (double)U3[i].y;
        ax += zx * zx - zy * zy;
        ay += 2.0 * zx * zy;
    }
    sx[t] = ax; sy[t] = ay;
    __syncthreads();
    for (int w = 128; w > 0; w >>= 1) {
        if (t < w) { sx[t] += sx[t + w]; sy[t] += sy[t + w]; }
        __syncthreads();
    }
    if (t == 0) spart[blockIdx.x] = make_double2(sx[0], sy[0]);
}

__global__ void k_scomb(const double2* __restrict__ spart, double2* __restrict__ Sp) {
    if (threadIdx.x != 0 || blockIdx.x != 0) return;
    double rx = 0.0, ry = 0.0;
    for (int i = 0; i < 64; ++i) { rx += spart[i].x; ry += spart[i].y; }
    Sp[0] = make_double2(rx + 1e-7, ry);
}

// ---------------- psf -> PADDED layout [3][256][256] (row 255/col 255 = 0) --
__global__ void k_psf(const float2* __restrict__ U3, const double2* __restrict__ Sp,
                      float* __restrict__ PSFP) {
    int idx = blockIdx.x * 256 + threadIdx.x;
    if (idx >= 3 * 256 * 256) return;
    int c = idx >> 16, r = (idx >> 8) & 255, q = idx & 255;
    float v = 0.0f;
    if (r < M && q < M) {
        double2 den = Sp[0];
        double inv = 1.0 / (den.x * den.x + den.y * den.y);
        float2 zf = U3[(c * M + r) * M + q];
        double zx = (double)zf.x, zy = (double)zf.y;
        double zr = zx * zx - zy * zy;
        double zi = 2.0 * zx * zy;
        v = (float)((zr * den.x + zi * den.y) * inv);
    }
    PSFP[idx] = v;
}

// ---------------- image HWC -> planar CHW ----------------
__global__ void k_transpose(const float* __restrict__ img, float* __restrict__ imgP) {
    int idx = blockIdx.x * 256 + threadIdx.x;
    if (idx >= 3 * NP) return;
    int c = idx / NP, ij = idx % NP;
    imgP[idx] = img[ij * 3 + c];
}

// ---------------- split-K tiled direct conv (f32) ----------------
// psf: global UNIFORM loads (scalar path, no LDS); image rows register-cached.
__global__ __launch_bounds__(128)
void k_conv(const float* __restrict__ imgP, const float* __restrict__ PSFP,
            float* __restrict__ PART) {
    constexpr int BI = 64, BJ = 32, DI = 8, DJ = 32;
    constexpr int ROWS = BI + DI - 1;   // 71
    constexpr int COLS = 64;            // 63 used + 1 pad
    __shared__ __align__(16) float simg[ROWS * COLS];

    int tid = threadIdx.x;
    int tj = tid & 7, ti = tid >> 3;
    int j0 = blockIdx.x * BJ;
    int bi = blockIdx.y;
    int i0 = (bi == 2) ? 96 : bi * 64;          // rows 0..63,64..127,96..159
    int cz = blockIdx.z;
    int c = cz >> 5, kz = cz & 31;
    int d0 = kz * DI;
    int rowBase = i0 + d0 - 80;
    const float* ip = imgP + (size_t)c * NP;
    const float* pb = PSFP + ((size_t)c << 16) + ((size_t)d0 << 8);

    float acc[4][4];
#pragma unroll
    for (int r = 0; r < 4; ++r)
#pragma unroll
        for (int q = 0; q < 4; ++q) acc[r][q] = 0.0f;

    for (int djt = 0; djt < 8; ++djt) {
        int dj0 = djt * DJ;
        int colBase = j0 + dj0 - 80;
        __syncthreads();
        for (int idx = tid; idx < ROWS * COLS; idx += 128) {
            int rr = idx >> 6, cc = idx & 63;
            int aa = rowBase + rr, bb = colBase + cc;
            float v = 0.0f;
            if (aa >= 0 && aa < M && bb >= 0 && bb < M && cc < 63) v = ip[aa * M + bb];
            simg[idx] = v;
        }
        __syncthreads();

#pragma unroll
        for (int dik = 0; dik < DI; ++dik) {
            const float* prow = pb + (dik << 8) + dj0;   // block-uniform -> SMEM
#pragma unroll
            for (int r = 0; r < 4; ++r) {
                const float* rp = &simg[(ti * 4 + r + dik) * COLS + tj * 4];
                float w[36];
#pragma unroll
                for (int v4 = 0; v4 < 9; ++v4) {
                    float4 t = *(const float4*)(rp + v4 * 4);
                    w[v4 * 4 + 0] = t.x; w[v4 * 4 + 1] = t.y;
                    w[v4 * 4 + 2] = t.z; w[v4 * 4 + 3] = t.w;
                }
#pragma unroll
                for (int djq = 0; djq < DJ; djq += 4) {
                    float p0 = prow[djq], p1 = prow[djq + 1];
                    float p2 = prow[djq + 2], p3 = prow[djq + 3];
#pragma unroll
                    for (int q = 0; q < 4; ++q) {
                        acc[r][q] += w[q + djq]     * p0 + w[q + djq + 1] * p1
                                   + w[q + djq + 2] * p2 + w[q + djq + 3] * p3;
                    }
                }
            }
        }
    }

    float* op = PART + (size_t)(c * 32 + kz) * (RESO * RESO);
#pragma unroll
    for (int r = 0; r < 4; ++r) {
        int i = i0 + ti * 4 + r;
        if (i < RESO) {
#pragma unroll
            for (int q = 0; q < 4; ++q) {
                int j = j0 + tj * 4 + q;
                op[i * RESO + j] = acc[r][q];
            }
        }
    }
}

// ---------------- reduce partials + clip + layout (i,j,c) ----------------
__global__ void k_out(const float* __restrict__ PART, float* __restrict__ out) {
    int idx = blockIdx.x * 256 + threadIdx.x;
    if (idx >= 3 * RESO * RESO) return;
    int c = idx / (RESO * RESO), ij = idx % (RESO * RESO);
    float s = 0.0f;
    for (int kz = 0; kz < 32; ++kz)
        s += PART[(size_t)(c * 32 + kz) * (RESO * RESO) + ij];
    s = fminf(fmaxf(s, 0.0f), 1.0f);
    int i = ij / RESO, j = ij % RESO;
    out[(i * RESO + j) * 3 + c] = s;
}

// ---------------------------------------------------------------------------
extern "C" void kernel_launch(void* const* d_in, const int* in_sizes, int n_in,
                              void* d_out, int out_size, void* d_ws, size_t ws_size,
                              hipStream_t stream) {
    const float* image = (const float*)d_in[0];   // (255,255,3)
    const float* depth = (const float*)d_in[1];   // (255,255)
    float* out = (float*)d_out;                   // (160,160,3)

    // workspace carve (256B aligned), ~20 MB total
    char* p = (char*)d_ws;
    auto alloc = [&](size_t bytes) { void* r = (void*)p; p += (bytes + 255) & ~(size_t)255; return r; };
    float*   meanp   = (float*)alloc(4);
    float*   leafVal = (float*)alloc(600 * 4);
    float2*  Wf    = (float2*)alloc((size_t)NP * 8);
    float2*  U2    = (float2*)alloc((size_t)3 * NP * 8);
    float2*  Hb    = (float2*)alloc((size_t)3 * NP * 8);
    float2*  Tb    = (float2*)alloc((size_t)3 * NP * 8);
    float2*  Eb    = (float2*)alloc((size_t)3 * NP * 8);
    float2*  Fb    = (float2*)alloc((size_t)3 * NP * 8);
    double2* spart = (double2*)alloc(64 * 16);
    double2* Sp    = (double2*)alloc(16);
    float*   PSFP  = (float*)alloc((size_t)3 * 256 * 256 * 4);
    float*   IMGP  = (float*)alloc((size_t)3 * NP * 4);
    float*   PART  = (float*)alloc((size_t)96 * RESO * RESO * 4);

    // exact python-f64 scalar path
    double dx = 0.002 / 255.0;
    double Lx = dx * 255.0;
    double ap = (Lx / 2.0) * 0.1 + 1e-7;
    float ap_f = (float)ap;

    double xstart = -(Lx / 2.0);
    double xstop  =  Lx / 2.0;
    double xstep  = (xstop - xstart) / 254.0;
    double fstart = -1.0 / (2.0 * dx);
    double fstop  =  1.0 / (2.0 * dx);
    double fstep  = (fstop - fstart) / 254.0;

    int g3 = (3 * NP + 255) / 256;   // 763
    int g1 = (NP + 255) / 256;       // 254

    k_transpose<<<g3, 256, 0, stream>>>(image, IMGP);
    k_leaf<<<(PWL.n + 255) / 256, 256, 0, stream>>>(depth, leafVal);
    k_comb<<<1, 256, 0, stream>>>(depth, leafVal, meanp);
    k_W32<<<g1, 256, 0, stream>>>(Wf);
    k_u2H<<<g3, 256, 0, stream>>>(meanp, U2, Hb,
                                  xstart, xstep, xstop,
                                  fstart, fstep, fstop, ap_f);

    dim3 gg(8, 8, 3), bb(256);
    // FU = (W*U2)*W   -> Eb
    k_cgemm32<<<gg, bb, 0, stream>>>(Wf, 0, U2, NP, Tb, 0, 0, 1.0f);
    k_cgemm32<<<gg, bb, 0, stream>>>(Tb, NP, Wf, 0, Eb, 0, 0, 1.0f);
    // FH = (W*H)*W    -> Fb
    k_cgemm32<<<gg, bb, 0, stream>>>(Wf, 0, Hb, NP, Tb, 0, 0, 1.0f);
    k_cgemm32<<<gg, bb, 0, stream>>>(Tb, NP, Wf, 0, Fb, 0, 0, 1.0f);
    // P = FH .* FU    -> Tb
    k_pmul<<<g3, 256, 0, stream>>>(Fb, Eb, Tb);
    // u3 = (1/255^2) * conj(W)*P*conj(W)  -> Fb
    k_cgemm32<<<gg, bb, 0, stream>>>(Wf, 0, Tb, NP, Eb, 1, 0, 1.0f / 255.0f);
    k_cgemm32<<<gg, bb, 0, stream>>>(Eb, NP, Wf, 0, Fb, 0, 1, 1.0f / 255.0f);

    k_sred<<<64, 256, 0, stream>>>(Fb, spart);
    k_scomb<<<1, 64, 0, stream>>>(spart, Sp);
    k_psf<<<768, 256, 0, stream>>>(Fb, Sp, PSFP);

    dim3 cg(5, 3, 96);
    k_conv<<<cg, 128, 0, stream>>>(IMGP, PSFP, PART);
    k_out<<<300, 256, 0, stream>>>(PART, out);
}

// Round 9
// 788.251 us; speedup vs baseline: 1.0507x; 1.0507x over previous
//
#include <hip/hip_runtime.h>
#include <hip/hip_bf16.h>
#include <math.h>

// ---------------------------------------------------------------------------
// MjCambrianOptics. Correctness-critical (R7-validated, DO NOT TOUCH):
//   * mean(depth) = numpy BUFFERED reduce: seed a[0], then sequential
//     += pairwise_sum(8192-chunk), 128-leaf/8-acc recursion.
//   * ki = fl32(2pi)/fl32(wl) f32 divide; linspace f64-cast; th/ph op order.
// R9 perf: conv COLS=68 (4-way max conflicts), row-window reuse (99 vs 288
// b128/djt), psf via scalar s_load path; 10 dispatches (fused prep/pmul/scomb).
// ---------------------------------------------------------------------------

constexpr int M   = 255;
constexpr int NP  = M * M;        // 65025
constexpr int RESO = 160;

// ---------------- numpy buffered-reduce pairwise forest (compile-time) ------
constexpr int MAXN = 1100;
struct PWForest {
    int kind[MAXN];
    int off[MAXN], len[MAXN];
    int li[MAXN], ri[MAXN];
    int lvl[MAXN];
    int nNode, nLeaf, maxLvl;
    int roots[16], nRoots;
};
constexpr int pwf_build(PWForest& T, int o, int n) {
    if (n <= 128) {
        int id = T.nNode++;
        T.kind[id] = 0; T.off[id] = o; T.len[id] = n;
        T.lvl[id] = 0; T.nLeaf++;
        return id;
    }
    int n2 = (n / 2) - ((n / 2) % 8);
    int a = pwf_build(T, o, n2);
    int b = pwf_build(T, o + n2, n - n2);
    int id = T.nNode++;
    T.kind[id] = 1; T.li[id] = a; T.ri[id] = b;
    int l = (T.lvl[a] > T.lvl[b] ? T.lvl[a] : T.lvl[b]) + 1;
    T.lvl[id] = l; if (l > T.maxLvl) T.maxLvl = l;
    return id;
}
constexpr PWForest pwf_make() {
    PWForest T{};
    int pos = 1, rem = NP - 1;            // reduce seeds with a[0]
    while (rem > 0) {
        int c = rem > 8192 ? 8192 : rem;  // nditer buffer = 8192 elements
        T.roots[T.nRoots++] = pwf_build(T, pos, c);
        pos += c; rem -= c;
    }
    return T;
}
constexpr PWForest PW = pwf_make();
static_assert(PW.nNode <= MAXN, "forest overflow");
static_assert(PW.nRoots == 8, "chunk count");

// ---------------- mean(depth): leaves + tree + finalize, ONE kernel ---------
__global__ void k_mean(const float* __restrict__ depth, float* __restrict__ meanp) {
    __shared__ float val[MAXN];
    int tid = threadIdx.x;
    for (int id = tid; id < PW.nNode; id += 256) {
        if (PW.kind[id] != 0) continue;
        const float* a = depth + PW.off[id];
        int n = PW.len[id];
        float r0 = a[0], r1 = a[1], r2 = a[2], r3 = a[3];
        float r4 = a[4], r5 = a[5], r6 = a[6], r7 = a[7];
        int lim = n - (n % 8);
        int i = 8;
        for (; i < lim; i += 8) {
            r0 += a[i + 0]; r1 += a[i + 1]; r2 += a[i + 2]; r3 += a[i + 3];
            r4 += a[i + 4]; r5 += a[i + 5]; r6 += a[i + 6]; r7 += a[i + 7];
        }
        float res = ((r0 + r1) + (r2 + r3)) + ((r4 + r5) + (r6 + r7));
        for (; i < n; ++i) res += a[i];
        val[id] = res;
    }
    __syncthreads();
    for (int l = 1; l <= PW.maxLvl; ++l) {
        for (int id = tid; id < PW.nNode; id += 256)
            if (PW.kind[id] == 1 && PW.lvl[id] == l)
                val[id] = val[PW.li[id]] + val[PW.ri[id]];
        __syncthreads();
    }
    if (tid == 0) {
        float io1 = depth[0];
        for (int r = 0; r < PW.nRoots; ++r)
            io1 = io1 + val[PW.roots[r]];
        meanp[0] = io1 / 65025.0f;
    }
}

// ---------------- prep mega-kernel: transpose + W + u2H ---------------------
// region A [0,3NP): image HWC->CHW; B [3NP,4NP): DFT W; C [4NP,7NP): u2,H
__global__ void k_prep(const float* __restrict__ img, float* __restrict__ imgP,
                       float2* __restrict__ W,
                       float2* __restrict__ U2, float2* __restrict__ Hb,
                       const float* __restrict__ meanp,
                       double xstart, double xstep, double xstop,
                       double fstart, double fstep, double fstop,
                       float ap_f) {
#pragma clang fp contract(off)
    int idx = blockIdx.x * 256 + threadIdx.x;
    if (idx < 3 * NP) {
        int c = idx / NP, ij = idx % NP;
        imgP[idx] = img[ij * 3 + c];
        return;
    }
    if (idx < 4 * NP) {
        int e = idx - 3 * NP;
        int n = e / M, k = e % M;
        int m = (n * k) % M;
        double ang = -2.0 * 3.14159265358979323846 * (double)m / 255.0;
        W[e] = make_float2((float)cos(ang), (float)sin(ang));
        return;
    }
    if (idx >= 7 * NP) return;
    int e = idx - 4 * NP;
    int c = e / NP, ij = e % NP, i = ij / M, j = ij % M;
    const float wls[3] = {6.1e-07f, 5.3e-07f, 4.7e-07f};
    float wl = wls[c];
    float ki = ((float)6.283185307179586) / wl;
    float d  = meanp[0];
    float d2 = d * d;

    float x  = (i == 254) ? (float)xstop : (float)((double)i * xstep + xstart);
    float y  = (j == 254) ? (float)xstop : (float)((double)j * xstep + xstart);
    float fx = (i == 254) ? (float)fstop : (float)((double)i * fstep + fstart);
    float fy = (j == 254) ? (float)fstop : (float)((double)j * fstep + fstart);

    float xx = x * x, yy = y * y;
    float X1Y1 = xx + yy;

    float s  = sqrtf(X1Y1 + d2);
    float th = ki * s;
    float A  = (sqrtf(X1Y1) / ap_f <= 1.0f) ? 1.0f : 0.0f;
    float2 u2v;
    if (A != 0.0f) u2v = make_float2((float)cos((double)th), (float)sin((double)th));
    else           u2v = make_float2(0.0f, 0.0f);

    float a = wl * fx, b = wl * fy;
    float arg = (1.0f - a * a) - b * b;
    float FXY = sqrtf(fmaxf(arg, 0.0f));
    float Hv  = (sqrtf(fx * fx + fy * fy) < (1.0f / wl)) ? 1.0f : 0.0f;
    float kd  = ki * d;
    float ph  = kd * FXY;
    float cph = (float)cos((double)ph), sph = (float)sin((double)ph);
    float2 hv = make_float2(Hv * cph, Hv * sph);

    U2[e] = u2v;
    Hb[e] = hv;
}

// ---------------- batched f32 complex GEMM, 32x32 tile, 2x2/thread ----------
// B2 != nullptr: B element = B[..] * B2[..] (fused elementwise complex mul)
__global__ __launch_bounds__(256)
void k_cgemm(const float2* __restrict__ A, int aBatch,
             const float2* __restrict__ B, const float2* __restrict__ B2,
             int bBatch, float2* __restrict__ C,
             int conjA, int conjB, float scale) {
    __shared__ float2 As[32][17];
    __shared__ float2 Bs[16][33];
    int c = blockIdx.z;
    int tx = threadIdx.x & 15, ty = threadIdx.x >> 4;
    int i0 = blockIdx.y * 32, j0 = blockIdx.x * 32;
    const float2* Ab = A + (size_t)c * aBatch;
    const float2* Bb = B + (size_t)c * bBatch;
    const float2* B2b = B2 ? (B2 + (size_t)c * bBatch) : nullptr;
    float2 a00 = {0,0}, a01 = {0,0}, a10 = {0,0}, a11 = {0,0};

    for (int kt = 0; kt < 16; ++kt) {
        int k0 = kt * 16;
#pragma unroll
        for (int s = 0; s < 2; ++s) {
            int idx = threadIdx.x + s * 256;
            int r = idx >> 4, cc = idx & 15;
            int gi = i0 + r, gk = k0 + cc;
            float2 v = (gi < M && gk < M) ? Ab[gi * M + gk] : make_float2(0.f, 0.f);
            if (conjA) v.y = -v.y;
            As[r][cc] = v;
            int r2 = idx >> 5, c2 = idx & 31;
            int gk2 = k0 + r2, gj = j0 + c2;
            float2 w = make_float2(0.f, 0.f);
            if (gk2 < M && gj < M) {
                w = Bb[gk2 * M + gj];
                if (B2b) {
                    float2 z = B2b[gk2 * M + gj];
                    w = make_float2(w.x * z.x - w.y * z.y, w.x * z.y + w.y * z.x);
                }
            }
            if (conjB) w.y = -w.y;
            Bs[r2][c2] = w;
        }
        __syncthreads();
#pragma unroll
        for (int kk = 0; kk < 16; ++kk) {
            float2 p = As[ty][kk], q = As[ty + 16][kk];
            float2 u = Bs[kk][tx], v = Bs[kk][tx + 16];
            a00.x += p.x * u.x - p.y * u.y;  a00.y += p.x * u.y + p.y * u.x;
            a01.x += p.x * v.x - p.y * v.y;  a01.y += p.x * v.y + p.y * v.x;
            a10.x += q.x * u.x - q.y * u.y;  a10.y += q.x * u.y + q.y * u.x;
            a11.x += q.x * v.x - q.y * v.y;  a11.y += q.x * v.y + q.y * v.x;
        }
        __syncthreads();
    }
    float2* Cb = C + (size_t)c * NP;
    int gi0 = i0 + ty, gi1 = i0 + ty + 16;
    int gj0 = j0 + tx, gj1 = j0 + tx + 16;
    if (gi0 < M && gj0 < M) Cb[gi0 * M + gj0] = make_float2(a00.x * scale, a00.y * scale);
    if (gi0 < M && gj1 < M) Cb[gi0 * M + gj1] = make_float2(a01.x * scale, a01.y * scale);
    if (gi1 < M && gj0 < M) Cb[gi1 * M + gj0] = make_float2(a10.x * scale, a10.y * scale);
    if (gi1 < M && gj1 < M) Cb[gi1 * M + gj1] = make_float2(a11.x * scale, a11.y * scale);
}

// ---------------- S = sum u3^2 (f64 accumulate over f32 u3) ----------------
__global__ void k_sred(const float2* __restrict__ U3, double2* __restrict__ spart) {
    __shared__ double sx[256], sy[256];
    int t = threadIdx.x;
    double ax = 0.0, ay = 0.0;
    for (int i = blockIdx.x * 256 + t; i < 3 * NP; i += 64 * 256) {
        double zx = (double)U3[i].x, zy = (double)U3[i].y;
        ax += zx * zx - zy * zy;
        ay += 2.0 * zx * zy;
    }
    sx[t] = ax; sy[t] = ay;
    __syncthreads();
    for (int w = 128; w > 0; w >>= 1) {
        if (t < w) { sx[t] += sx[t + w]; sy[t] += sy[t + w]; }
        __syncthreads();
    }
    if (t == 0) spart[blockIdx.x] = make_double2(sx[0], sy[0]);
}

// ---------------- psf (fused scomb) -> PADDED [3][256][256] -----------------
__global__ void k_psf(const float2* __restrict__ U3, const double2* __restrict__ spart,
                      float* __restrict__ PSFP) {
    int idx = blockIdx.x * 256 + threadIdx.x;
    if (idx >= 3 * 256 * 256) return;
    double rx = 0.0, ry = 0.0;
    for (int i = 0; i < 64; ++i) { rx += spart[i].x; ry += spart[i].y; }
    double dsx = rx + 1e-7, dsy = ry;            // same association as R8 scomb
    int c = idx >> 16, r = (idx >> 8) & 255, q = idx & 255;
    float v = 0.0f;
    if (r < M && q < M) {
        double inv = 1.0 / (dsx * dsx + dsy * dsy);
        float2 zf = U3[(c * M + r) * M + q];
        double zx = (double)zf.x, zy = (double)zf.y;
        double zr = zx * zx - zy * zy;
        double zi = 2.0 * zx * zy;
        v = (float)((zr * dsx + zi * dsy) * inv);
    }
    PSFP[idx] = v;
}

// ---------------- split-K tiled direct conv (f32) ----------------
// simg COLS=68 (4-way max), row-window reuse (each row read once per djt),
// psf via wave-uniform global loads (scalar path).
__global__ __launch_bounds__(128)
void k_conv(const float* __restrict__ imgP, const float* __restrict__ PSFP,
            float* __restrict__ PART) {
    constexpr int BJ = 32, DI = 8;
    constexpr int ROWS = 71;            // 64 + 8 - 1
    constexpr int COLS = 68;            // 63 used + pad; 68 % 8 == 4
    __shared__ __align__(16) float simg[ROWS * COLS];

    int tid = threadIdx.x;
    int tj = tid & 7, ti = tid >> 3;
    int j0 = blockIdx.x * BJ;
    int bi = blockIdx.y;
    int i0 = (bi == 2) ? 96 : bi * 64;
    int cz = blockIdx.z;
    int c = cz >> 5, kz = cz & 31;
    int d0 = kz * DI;
    int rowBase = i0 + d0 - 80;
    const float* ip = imgP + (size_t)c * NP;
    const float* pp = PSFP + ((size_t)c << 16) + ((size_t)d0 << 8);

    float acc[4][4];
#pragma unroll
    for (int r = 0; r < 4; ++r)
#pragma unroll
        for (int q = 0; q < 4; ++q) acc[r][q] = 0.0f;

    for (int djt = 0; djt < 8; ++djt) {
        int dj0 = djt * BJ;
        int colBase = j0 + dj0 - 80;
        __syncthreads();
        for (int idx = tid; idx < ROWS * COLS; idx += 128) {
            int rr = idx / COLS, cc = idx - rr * COLS;
            int aa = rowBase + rr, bb = colBase + cc;
            float v = 0.0f;
            if (aa >= 0 && aa < M && bb >= 0 && bb < M && cc < 63) v = ip[aa * M + bb];
            simg[idx] = v;
        }
        __syncthreads();

#pragma unroll
        for (int rl = 0; rl < 11; ++rl) {
            const float* rp = &simg[(ti * 4 + rl) * COLS + tj * 4];
            float w[36];
#pragma unroll
            for (int v4 = 0; v4 < 9; ++v4) {
                float4 t = *(const float4*)(rp + v4 * 4);
                w[v4 * 4 + 0] = t.x; w[v4 * 4 + 1] = t.y;
                w[v4 * 4 + 2] = t.z; w[v4 * 4 + 3] = t.w;
            }
#pragma unroll
            for (int dik = 0; dik < 8; ++dik) {
                if (dik > rl || rl - dik > 3) continue;   // folded at compile time
                int r = rl - dik;
                const float* prow = pp + (dik << 8) + dj0; // wave-uniform -> s_load
#pragma unroll
                for (int djq = 0; djq < 32; djq += 4) {
                    float p0 = prow[djq], p1 = prow[djq + 1];
                    float p2 = prow[djq + 2], p3 = prow[djq + 3];
#pragma unroll
                    for (int q = 0; q < 4; ++q) {
                        acc[r][q] += w[q + djq]     * p0 + w[q + djq + 1] * p1
                                   + w[q + djq + 2] * p2 + w[q + djq + 3] * p3;
                    }
                }
            }
        }
    }

    float* op = PART + (size_t)(c * 32 + kz) * (RESO * RESO);
#pragma unroll
    for (int r = 0; r < 4; ++r) {
        int i = i0 + ti * 4 + r;
        if (i < RESO) {
#pragma unroll
            for (int q = 0; q < 4; ++q) {
                int j = j0 + tj * 4 + q;
                op[i * RESO + j] = acc[r][q];
            }
        }
    }
}

// ---------------- reduce partials + clip + layout (i,j,c) ----------------
__global__ void k_out(const float* __restrict__ PART, float* __restrict__ out) {
    int idx = blockIdx.x * 256 + threadIdx.x;
    if (idx >= 3 * RESO * RESO) return;
    int c = idx / (RESO * RESO), ij = idx % (RESO * RESO);
    float s = 0.0f;
    for (int kz = 0; kz < 32; ++kz)
        s += PART[(size_t)(c * 32 + kz) * (RESO * RESO) + ij];
    s = fminf(fmaxf(s, 0.0f), 1.0f);
    int i = ij / RESO, j = ij % RESO;
    out[(i * RESO + j) * 3 + c] = s;
}

// ---------------------------------------------------------------------------
extern "C" void kernel_launch(void* const* d_in, const int* in_sizes, int n_in,
                              void* d_out, int out_size, void* d_ws, size_t ws_size,
                              hipStream_t stream) {
    const float* image = (const float*)d_in[0];   // (255,255,3)
    const float* depth = (const float*)d_in[1];   // (255,255)
    float* out = (float*)d_out;                   // (160,160,3)

    // workspace carve (256B aligned), ~21 MB
    char* p = (char*)d_ws;
    auto alloc = [&](size_t bytes) { void* r = (void*)p; p += (bytes + 255) & ~(size_t)255; return r; };
    float*   meanp = (float*)alloc(4);
    float2*  Wf    = (float2*)alloc((size_t)NP * 8);
    float2*  UH    = (float2*)alloc((size_t)6 * NP * 8);   // U2 | Hb
    float2*  Td    = (float2*)alloc((size_t)6 * NP * 8);   // stage 1 out
    float2*  EF    = (float2*)alloc((size_t)6 * NP * 8);   // FU | FH
    float2*  U3    = (float2*)alloc((size_t)3 * NP * 8);
    double2* spart = (double2*)alloc(64 * 16);
    float*   PSFP  = (float*)alloc((size_t)3 * 256 * 256 * 4);
    float*   IMGP  = (float*)alloc((size_t)3 * NP * 4);
    float*   PART  = (float*)alloc((size_t)96 * RESO * RESO * 4);

    float2* U2 = UH;
    float2* Hb = UH + (size_t)3 * NP;

    // exact python-f64 scalar path
    double dx = 0.002 / 255.0;
    double Lx = dx * 255.0;
    double ap = (Lx / 2.0) * 0.1 + 1e-7;
    float ap_f = (float)ap;

    double xstart = -(Lx / 2.0);
    double xstop  =  Lx / 2.0;
    double xstep  = (xstop - xstart) / 254.0;
    double fstart = -1.0 / (2.0 * dx);
    double fstop  =  1.0 / (2.0 * dx);
    double fstep  = (fstop - fstart) / 254.0;

    k_mean<<<1, 256, 0, stream>>>(depth, meanp);
    int gprep = (7 * NP + 255) / 256;   // 1778
    k_prep<<<gprep, 256, 0, stream>>>(image, IMGP, Wf, U2, Hb, meanp,
                                      xstart, xstep, xstop,
                                      fstart, fstep, fstop, ap_f);

    dim3 bb(256);
    // stage1: Td[z] = W * UH[z]   (z=6: FU path 0..2, FH path 3..5)
    k_cgemm<<<dim3(8, 8, 6), bb, 0, stream>>>(Wf, 0, UH, nullptr, NP, Td, 0, 0, 1.0f);
    // stage2: EF[z] = Td[z] * W
    k_cgemm<<<dim3(8, 8, 6), bb, 0, stream>>>(Td, NP, Wf, nullptr, 0, EF, 0, 0, 1.0f);
    // stage3: Td[c] = conj(W) * (FH .* FU) / 255   (fused pmul: B=FH, B2=FU)
    k_cgemm<<<dim3(8, 8, 3), bb, 0, stream>>>(Wf, 0, EF + (size_t)3 * NP, EF, NP,
                                              Td, 1, 0, 1.0f / 255.0f);
    // stage4: U3[c] = Td[c] * conj(W) / 255
    k_cgemm<<<dim3(8, 8, 3), bb, 0, stream>>>(Td, NP, Wf, nullptr, 0, U3, 0, 1,
                                              1.0f / 255.0f);

    k_sred<<<64, 256, 0, stream>>>(U3, spart);
    k_psf<<<768, 256, 0, stream>>>(U3, spart, PSFP);

    k_conv<<<dim3(5, 3, 96), 128, 0, stream>>>(IMGP, PSFP, PART);
    k_out<<<300, 256, 0, stream>>>(PART, out);
}

// Round 10
// 758.391 us; speedup vs baseline: 1.0921x; 1.0394x over previous
//
#include <hip/hip_runtime.h>
#include <hip/hip_bf16.h>
#include <math.h>

// ---------------------------------------------------------------------------
// MjCambrianOptics. Correctness-critical (R7-validated, DO NOT TOUCH):
//   * mean(depth) = numpy BUFFERED reduce: seed a[0], then sequential
//     += pairwise_sum(8192-chunk), 128-leaf/8-acc recursion.
//   * ki = fl32(2pi)/fl32(wl) f32 divide; linspace f64-cast; th/ph op order.
// R10 perf: conv inner loop is DS-only (psf tile in LDS, broadcast reads ->
// register prow[32] per dik; no SMEM/VMEM in the FMA loop -> fine-grained
// lgkmcnt instead of full drains). COLS=68 keeps b128 bank-tiling perfect.
// ---------------------------------------------------------------------------

constexpr int M   = 255;
constexpr int NP  = M * M;        // 65025
constexpr int RESO = 160;

// ---------------- numpy buffered-reduce pairwise forest (compile-time) ------
constexpr int MAXN = 1100;
struct PWForest {
    int kind[MAXN];
    int off[MAXN], len[MAXN];
    int li[MAXN], ri[MAXN];
    int lvl[MAXN];
    int nNode, nLeaf, maxLvl;
    int roots[16], nRoots;
};
constexpr int pwf_build(PWForest& T, int o, int n) {
    if (n <= 128) {
        int id = T.nNode++;
        T.kind[id] = 0; T.off[id] = o; T.len[id] = n;
        T.lvl[id] = 0; T.nLeaf++;
        return id;
    }
    int n2 = (n / 2) - ((n / 2) % 8);
    int a = pwf_build(T, o, n2);
    int b = pwf_build(T, o + n2, n - n2);
    int id = T.nNode++;
    T.kind[id] = 1; T.li[id] = a; T.ri[id] = b;
    int l = (T.lvl[a] > T.lvl[b] ? T.lvl[a] : T.lvl[b]) + 1;
    T.lvl[id] = l; if (l > T.maxLvl) T.maxLvl = l;
    return id;
}
constexpr PWForest pwf_make() {
    PWForest T{};
    int pos = 1, rem = NP - 1;            // reduce seeds with a[0]
    while (rem > 0) {
        int c = rem > 8192 ? 8192 : rem;  // nditer buffer = 8192 elements
        T.roots[T.nRoots++] = pwf_build(T, pos, c);
        pos += c; rem -= c;
    }
    return T;
}
constexpr PWForest PW = pwf_make();
static_assert(PW.nNode <= MAXN, "forest overflow");
static_assert(PW.nRoots == 8, "chunk count");

// ---------------- mean(depth): leaves + tree + finalize, ONE kernel ---------
__global__ void k_mean(const float* __restrict__ depth, float* __restrict__ meanp) {
    __shared__ float val[MAXN];
    int tid = threadIdx.x;
    for (int id = tid; id < PW.nNode; id += 256) {
        if (PW.kind[id] != 0) continue;
        const float* a = depth + PW.off[id];
        int n = PW.len[id];
        float r0 = a[0], r1 = a[1], r2 = a[2], r3 = a[3];
        float r4 = a[4], r5 = a[5], r6 = a[6], r7 = a[7];
        int lim = n - (n % 8);
        int i = 8;
        for (; i < lim; i += 8) {
            r0 += a[i + 0]; r1 += a[i + 1]; r2 += a[i + 2]; r3 += a[i + 3];
            r4 += a[i + 4]; r5 += a[i + 5]; r6 += a[i + 6]; r7 += a[i + 7];
        }
        float res = ((r0 + r1) + (r2 + r3)) + ((r4 + r5) + (r6 + r7));
        for (; i < n; ++i) res += a[i];
        val[id] = res;
    }
    __syncthreads();
    for (int l = 1; l <= PW.maxLvl; ++l) {
        for (int id = tid; id < PW.nNode; id += 256)
            if (PW.kind[id] == 1 && PW.lvl[id] == l)
                val[id] = val[PW.li[id]] + val[PW.ri[id]];
        __syncthreads();
    }
    if (tid == 0) {
        float io1 = depth[0];
        for (int r = 0; r < PW.nRoots; ++r)
            io1 = io1 + val[PW.roots[r]];
        meanp[0] = io1 / 65025.0f;
    }
}

// ---------------- prep mega-kernel: transpose + W + u2H ---------------------
__global__ void k_prep(const float* __restrict__ img, float* __restrict__ imgP,
                       float2* __restrict__ W,
                       float2* __restrict__ U2, float2* __restrict__ Hb,
                       const float* __restrict__ meanp,
                       double xstart, double xstep, double xstop,
                       double fstart, double fstep, double fstop,
                       float ap_f) {
#pragma clang fp contract(off)
    int idx = blockIdx.x * 256 + threadIdx.x;
    if (idx < 3 * NP) {
        int c = idx / NP, ij = idx % NP;
        imgP[idx] = img[ij * 3 + c];
        return;
    }
    if (idx < 4 * NP) {
        int e = idx - 3 * NP;
        int n = e / M, k = e % M;
        int m = (n * k) % M;
        double ang = -2.0 * 3.14159265358979323846 * (double)m / 255.0;
        W[e] = make_float2((float)cos(ang), (float)sin(ang));
        return;
    }
    if (idx >= 7 * NP) return;
    int e = idx - 4 * NP;
    int c = e / NP, ij = e % NP, i = ij / M, j = ij % M;
    const float wls[3] = {6.1e-07f, 5.3e-07f, 4.7e-07f};
    float wl = wls[c];
    float ki = ((float)6.283185307179586) / wl;
    float d  = meanp[0];
    float d2 = d * d;

    float x  = (i == 254) ? (float)xstop : (float)((double)i * xstep + xstart);
    float y  = (j == 254) ? (float)xstop : (float)((double)j * xstep + xstart);
    float fx = (i == 254) ? (float)fstop : (float)((double)i * fstep + fstart);
    float fy = (j == 254) ? (float)fstop : (float)((double)j * fstep + fstart);

    float xx = x * x, yy = y * y;
    float X1Y1 = xx + yy;

    float s  = sqrtf(X1Y1 + d2);
    float th = ki * s;
    float A  = (sqrtf(X1Y1) / ap_f <= 1.0f) ? 1.0f : 0.0f;
    float2 u2v;
    if (A != 0.0f) u2v = make_float2((float)cos((double)th), (float)sin((double)th));
    else           u2v = make_float2(0.0f, 0.0f);

    float a = wl * fx, b = wl * fy;
    float arg = (1.0f - a * a) - b * b;
    float FXY = sqrtf(fmaxf(arg, 0.0f));
    float Hv  = (sqrtf(fx * fx + fy * fy) < (1.0f / wl)) ? 1.0f : 0.0f;
    float kd  = ki * d;
    float ph  = kd * FXY;
    float cph = (float)cos((double)ph), sph = (float)sin((double)ph);
    float2 hv = make_float2(Hv * cph, Hv * sph);

    U2[e] = u2v;
    Hb[e] = hv;
}

// ---------------- batched f32 complex GEMM, 32x32 tile, 2x2/thread ----------
__global__ __launch_bounds__(256)
void k_cgemm(const float2* __restrict__ A, int aBatch,
             const float2* __restrict__ B, const float2* __restrict__ B2,
             int bBatch, float2* __restrict__ C,
             int conjA, int conjB, float scale) {
    __shared__ float2 As[32][17];
    __shared__ float2 Bs[16][33];
    int c = blockIdx.z;
    int tx = threadIdx.x & 15, ty = threadIdx.x >> 4;
    int i0 = blockIdx.y * 32, j0 = blockIdx.x * 32;
    const float2* Ab = A + (size_t)c * aBatch;
    const float2* Bb = B + (size_t)c * bBatch;
    const float2* B2b = B2 ? (B2 + (size_t)c * bBatch) : nullptr;
    float2 a00 = {0,0}, a01 = {0,0}, a10 = {0,0}, a11 = {0,0};

    for (int kt = 0; kt < 16; ++kt) {
        int k0 = kt * 16;
#pragma unroll
        for (int s = 0; s < 2; ++s) {
            int idx = threadIdx.x + s * 256;
            int r = idx >> 4, cc = idx & 15;
            int gi = i0 + r, gk = k0 + cc;
            float2 v = (gi < M && gk < M) ? Ab[gi * M + gk] : make_float2(0.f, 0.f);
            if (conjA) v.y = -v.y;
            As[r][cc] = v;
            int r2 = idx >> 5, c2 = idx & 31;
            int gk2 = k0 + r2, gj = j0 + c2;
            float2 w = make_float2(0.f, 0.f);
            if (gk2 < M && gj < M) {
                w = Bb[gk2 * M + gj];
                if (B2b) {
                    float2 z = B2b[gk2 * M + gj];
                    w = make_float2(w.x * z.x - w.y * z.y, w.x * z.y + w.y * z.x);
                }
            }
            if (conjB) w.y = -w.y;
            Bs[r2][c2] = w;
        }
        __syncthreads();
#pragma unroll
        for (int kk = 0; kk < 16; ++kk) {
            float2 p = As[ty][kk], q = As[ty + 16][kk];
            float2 u = Bs[kk][tx], v = Bs[kk][tx + 16];
            a00.x += p.x * u.x - p.y * u.y;  a00.y += p.x * u.y + p.y * u.x;
            a01.x += p.x * v.x - p.y * v.y;  a01.y += p.x * v.y + p.y * v.x;
            a10.x += q.x * u.x - q.y * u.y;  a10.y += q.x * u.y + q.y * u.x;
            a11.x += q.x * v.x - q.y * v.y;  a11.y += q.x * v.y + q.y * v.x;
        }
        __syncthreads();
    }
    float2* Cb = C + (size_t)c * NP;
    int gi0 = i0 + ty, gi1 = i0 + ty + 16;
    int gj0 = j0 + tx, gj1 = j0 + tx + 16;
    if (gi0 < M && gj0 < M) Cb[gi0 * M + gj0] = make_float2(a00.x * scale, a00.y * scale);
    if (gi0 < M && gj1 < M) Cb[gi0 * M + gj1] = make_float2(a01.x * scale, a01.y * scale);
    if (gi1 < M && gj0 < M) Cb[gi1 * M + gj0] = make_float2(a10.x * scale, a10.y * scale);
    if (gi1 < M && gj1 < M) Cb[gi1 * M + gj1] = make_float2(a11.x * scale, a11.y * scale);
}

// ---------------- S = sum u3^2 (f64 accumulate over f32 u3) ----------------
__global__ void k_sred(const float2* __restrict__ U3, double2* __restrict__ spart) {
    __shared__ double sx[256], sy[256];
    int t = threadIdx.x;
    double ax = 0.0, ay = 0.0;
    for (int i = blockIdx.x * 256 + t; i < 3 * NP; i += 64 * 256) {
        double zx = (double)U3[i].x, zy = (double)U3[i].y;
        ax += zx * zx - zy * zy;
        ay += 2.0 * zx * zy;
    }
    sx[t] = ax; sy[t] = ay;
    __syncthreads();
    for (int w = 128; w > 0; w >>= 1) {
        if (t < w) { sx[t] += sx[t + w]; sy[t] += sy[t + w]; }
        __syncthreads();
    }
    if (t == 0) spart[blockIdx.x] = make_double2(sx[0], sy[0]);
}

// ---------------- psf (fused scomb) -> PADDED [3][256][256] -----------------
__global__ void k_psf(const float2* __restrict__ U3, const double2* __restrict__ spart,
                      float* __restrict__ PSFP) {
    int idx = blockIdx.x * 256 + threadIdx.x;
    if (idx >= 3 * 256 * 256) return;
    double rx = 0.0, ry = 0.0;
    for (int i = 0; i < 64; ++i) { rx += spart[i].x; ry += spart[i].y; }
    double dsx = rx + 1e-7, dsy = ry;
    int c = idx >> 16, r = (idx >> 8) & 255, q = idx & 255;
    float v = 0.0f;
    if (r < M && q < M) {
        double inv = 1.0 / (dsx * dsx + dsy * dsy);
        float2 zf = U3[(c * M + r) * M + q];
        double zx = (double)zf.x, zy = (double)zf.y;
        double zr = zx * zx - zy * zy;
        double zi = 2.0 * zx * zy;
        v = (float)((zr * dsx + zi * dsy) * inv);
    }
    PSFP[idx] = v;
}

// ---------------- split-K tiled direct conv (f32), DS-only inner loop -------
__global__ __launch_bounds__(128)
void k_conv(const float* __restrict__ imgP, const float* __restrict__ PSFP,
            float* __restrict__ PART) {
    constexpr int BJ = 32, DI = 8;
    constexpr int ROWS = 71;            // 64 + 8 - 1
    constexpr int COLS = 68;            // 63 used + pad; b128 bank-tiling OK
    __shared__ __align__(16) float simg[ROWS * COLS];
    __shared__ __align__(16) float spsf[DI * BJ];   // 8 x 32 psf tile

    int tid = threadIdx.x;
    int tj = tid & 7, ti = tid >> 3;
    int j0 = blockIdx.x * BJ;
    int bi = blockIdx.y;
    int i0 = (bi == 2) ? 96 : bi * 64;
    int cz = blockIdx.z;
    int c = cz >> 5, kz = cz & 31;
    int d0 = kz * DI;
    int rowBase = i0 + d0 - 80;
    const float* ip = imgP + (size_t)c * NP;
    const float* pp = PSFP + ((size_t)c << 16) + ((size_t)d0 << 8);

    float acc[4][4];
#pragma unroll
    for (int r = 0; r < 4; ++r)
#pragma unroll
        for (int q = 0; q < 4; ++q) acc[r][q] = 0.0f;

    for (int djt = 0; djt < 8; ++djt) {
        int dj0 = djt * BJ;
        int colBase = j0 + dj0 - 80;
        __syncthreads();
        for (int idx = tid; idx < ROWS * COLS; idx += 128) {
            int rr = idx / COLS, cc = idx - rr * COLS;
            int aa = rowBase + rr, bb = colBase + cc;
            float v = 0.0f;
            if (aa >= 0 && aa < M && bb >= 0 && bb < M && cc < 63) v = ip[aa * M + bb];
            simg[idx] = v;
        }
        // psf tile: PSFP is padded [256][256] w/ zero row/col 255 -> no guards
        for (int idx = tid; idx < DI * BJ; idx += 128) {
            int r = idx >> 5, q = idx & 31;
            spsf[idx] = pp[(r << 8) + dj0 + q];
        }
        __syncthreads();

#pragma unroll
        for (int dik = 0; dik < DI; ++dik) {
            // psf row -> registers via LDS broadcast (same addr across lanes)
            float prow[32];
#pragma unroll
            for (int v4 = 0; v4 < 8; ++v4) {
                float4 t = *(const float4*)(&spsf[dik * 32 + v4 * 4]);
                prow[v4 * 4 + 0] = t.x; prow[v4 * 4 + 1] = t.y;
                prow[v4 * 4 + 2] = t.z; prow[v4 * 4 + 3] = t.w;
            }
#pragma unroll
            for (int r = 0; r < 4; ++r) {
                const float* rp = &simg[(ti * 4 + r + dik) * COLS + tj * 4];
                float w[36];
#pragma unroll
                for (int v4 = 0; v4 < 9; ++v4) {
                    float4 t = *(const float4*)(rp + v4 * 4);
                    w[v4 * 4 + 0] = t.x; w[v4 * 4 + 1] = t.y;
                    w[v4 * 4 + 2] = t.z; w[v4 * 4 + 3] = t.w;
                }
#pragma unroll
                for (int djq = 0; djq < 32; djq += 4) {
#pragma unroll
                    for (int q = 0; q < 4; ++q) {
                        acc[r][q] += w[q + djq]     * prow[djq]
                                   + w[q + djq + 1] * prow[djq + 1]
                                   + w[q + djq + 2] * prow[djq + 2]
                                   + w[q + djq + 3] * prow[djq + 3];
                    }
                }
            }
        }
    }

    float* op = PART + (size_t)(c * 32 + kz) * (RESO * RESO);
#pragma unroll
    for (int r = 0; r < 4; ++r) {
        int i = i0 + ti * 4 + r;
        if (i < RESO) {
#pragma unroll
            for (int q = 0; q < 4; ++q) {
                int j = j0 + tj * 4 + q;
                op[i * RESO + j] = acc[r][q];
            }
        }
    }
}

// ---------------- reduce partials + clip + layout (i,j,c) ----------------
__global__ void k_out(const float* __restrict__ PART, float* __restrict__ out) {
    int idx = blockIdx.x * 256 + threadIdx.x;
    if (idx >= 3 * RESO * RESO) return;
    int c = idx / (RESO * RESO), ij = idx % (RESO * RESO);
    float s = 0.0f;
    for (int kz = 0; kz < 32; ++kz)
        s += PART[(size_t)(c * 32 + kz) * (RESO * RESO) + ij];
    s = fminf(fmaxf(s, 0.0f), 1.0f);
    int i = ij / RESO, j = ij % RESO;
    out[(i * RESO + j) * 3 + c] = s;
}

// ---------------------------------------------------------------------------
extern "C" void kernel_launch(void* const* d_in, const int* in_sizes, int n_in,
                              void* d_out, int out_size, void* d_ws, size_t ws_size,
                              hipStream_t stream) {
    const float* image = (const float*)d_in[0];   // (255,255,3)
    const float* depth = (const float*)d_in[1];   // (255,255)
    float* out = (float*)d_out;                   // (160,160,3)

    // workspace carve (256B aligned), ~21 MB
    char* p = (char*)d_ws;
    auto alloc = [&](size_t bytes) { void* r = (void*)p; p += (bytes + 255) & ~(size_t)255; return r; };
    float*   meanp = (float*)alloc(4);
    float2*  Wf    = (float2*)alloc((size_t)NP * 8);
    float2*  UH    = (float2*)alloc((size_t)6 * NP * 8);   // U2 | Hb
    float2*  Td    = (float2*)alloc((size_t)6 * NP * 8);   // stage 1 out
    float2*  EF    = (float2*)alloc((size_t)6 * NP * 8);   // FU | FH
    float2*  U3    = (float2*)alloc((size_t)3 * NP * 8);
    double2* spart = (double2*)alloc(64 * 16);
    float*   PSFP  = (float*)alloc((size_t)3 * 256 * 256 * 4);
    float*   IMGP  = (float*)alloc((size_t)3 * NP * 4);
    float*   PART  = (float*)alloc((size_t)96 * RESO * RESO * 4);

    float2* U2 = UH;
    float2* Hb = UH + (size_t)3 * NP;

    // exact python-f64 scalar path
    double dx = 0.002 / 255.0;
    double Lx = dx * 255.0;
    double ap = (Lx / 2.0) * 0.1 + 1e-7;
    float ap_f = (float)ap;

    double xstart = -(Lx / 2.0);
    double xstop  =  Lx / 2.0;
    double xstep  = (xstop - xstart) / 254.0;
    double fstart = -1.0 / (2.0 * dx);
    double fstop  =  1.0 / (2.0 * dx);
    double fstep  = (fstop - fstart) / 254.0;

    k_mean<<<1, 256, 0, stream>>>(depth, meanp);
    int gprep = (7 * NP + 255) / 256;   // 1778
    k_prep<<<gprep, 256, 0, stream>>>(image, IMGP, Wf, U2, Hb, meanp,
                                      xstart, xstep, xstop,
                                      fstart, fstep, fstop, ap_f);

    dim3 bb(256);
    // stage1: Td[z] = W * UH[z]   (z=6: FU path 0..2, FH path 3..5)
    k_cgemm<<<dim3(8, 8, 6), bb, 0, stream>>>(Wf, 0, UH, nullptr, NP, Td, 0, 0, 1.0f);
    // stage2: EF[z] = Td[z] * W
    k_cgemm<<<dim3(8, 8, 6), bb, 0, stream>>>(Td, NP, Wf, nullptr, 0, EF, 0, 0, 1.0f);
    // stage3: Td[c] = conj(W) * (FH .* FU) / 255   (fused pmul)
    k_cgemm<<<dim3(8, 8, 3), bb, 0, stream>>>(Wf, 0, EF + (size_t)3 * NP, EF, NP,
                                              Td, 1, 0, 1.0f / 255.0f);
    // stage4: U3[c] = Td[c] * conj(W) / 255
    k_cgemm<<<dim3(8, 8, 3), bb, 0, stream>>>(Td, NP, Wf, nullptr, 0, U3, 0, 1,
                                              1.0f / 255.0f);

    k_sred<<<64, 256, 0, stream>>>(U3, spart);
    k_psf<<<768, 256, 0, stream>>>(U3, spart, PSFP);

    k_conv<<<dim3(5, 3, 96), 128, 0, stream>>>(IMGP, PSFP, PART);
    k_out<<<300, 256, 0, stream>>>(PART, out);
}

// Round 11
// 563.894 us; speedup vs baseline: 1.4688x; 1.3449x over previous
//
#include <hip/hip_runtime.h>
#include <hip/hip_bf16.h>
#include <math.h>

// ---------------------------------------------------------------------------
// MjCambrianOptics. Correctness-critical (R7-validated, DO NOT TOUCH):
//   * mean(depth) = numpy BUFFERED reduce: seed a[0], then sequential
//     += pairwise_sum(8192-chunk), 128-leaf/8-acc recursion.
//   * ki = fl32(2pi)/fl32(wl) f32 divide; linspace f64-cast; th/ph op order.
// R11: conv -> MFMA (banded-Toeplitz implicit GEMM, split-bf16 hi/lo, no LDS).
// ---------------------------------------------------------------------------

constexpr int M   = 255;
constexpr int NP  = M * M;        // 65025
constexpr int RESO = 160;

// IMG2 (padded bf16 image, hi|lo): [side][ch][row 0..415][col 0..447]
constexpr int IMG_ROWS = 416, IMG_COLS = 448;
constexpr int IMG_CH   = IMG_ROWS * IMG_COLS;      // 186368
constexpr int IMG_SIDE = 3 * IMG_CH;               // 559104
// P4 (4-shift-copy padded bf16 psf, hi|lo): [side][ch][di 0..255][r 0..3][e 0..319]
constexpr int P4_DI   = 4 * 320;                   // 1280
constexpr int P4_CH   = 256 * P4_DI;               // 327680
constexpr int P4_SIDE = 3 * P4_CH;                 // 983040

typedef __attribute__((ext_vector_type(8))) short short8;
typedef __attribute__((ext_vector_type(4))) float f32x4;

__device__ __forceinline__ unsigned short f2bf(float f) {
    unsigned int u = __float_as_uint(f);
    unsigned int r = (u + 0x7fffu + ((u >> 16) & 1u)) >> 16;
    return (unsigned short)r;
}
__device__ __forceinline__ float bf2f(unsigned short h) {
    return __uint_as_float(((unsigned int)h) << 16);
}

// ---------------- numpy buffered-reduce pairwise forest (compile-time) ------
constexpr int MAXN = 1100;
struct PWForest {
    int kind[MAXN];
    int off[MAXN], len[MAXN];
    int li[MAXN], ri[MAXN];
    int lvl[MAXN];
    int nNode, nLeaf, maxLvl;
    int roots[16], nRoots;
};
constexpr int pwf_build(PWForest& T, int o, int n) {
    if (n <= 128) {
        int id = T.nNode++;
        T.kind[id] = 0; T.off[id] = o; T.len[id] = n;
        T.lvl[id] = 0; T.nLeaf++;
        return id;
    }
    int n2 = (n / 2) - ((n / 2) % 8);
    int a = pwf_build(T, o, n2);
    int b = pwf_build(T, o + n2, n - n2);
    int id = T.nNode++;
    T.kind[id] = 1; T.li[id] = a; T.ri[id] = b;
    int l = (T.lvl[a] > T.lvl[b] ? T.lvl[a] : T.lvl[b]) + 1;
    T.lvl[id] = l; if (l > T.maxLvl) T.maxLvl = l;
    return id;
}
constexpr PWForest pwf_make() {
    PWForest T{};
    int pos = 1, rem = NP - 1;            // reduce seeds with a[0]
    while (rem > 0) {
        int c = rem > 8192 ? 8192 : rem;  // nditer buffer = 8192 elements
        T.roots[T.nRoots++] = pwf_build(T, pos, c);
        pos += c; rem -= c;
    }
    return T;
}
constexpr PWForest PW = pwf_make();
static_assert(PW.nNode <= MAXN, "forest overflow");
static_assert(PW.nRoots == 8, "chunk count");

__global__ void k_mean(const float* __restrict__ depth, float* __restrict__ meanp) {
    __shared__ float val[MAXN];
    int tid = threadIdx.x;
    for (int id = tid; id < PW.nNode; id += 256) {
        if (PW.kind[id] != 0) continue;
        const float* a = depth + PW.off[id];
        int n = PW.len[id];
        float r0 = a[0], r1 = a[1], r2 = a[2], r3 = a[3];
        float r4 = a[4], r5 = a[5], r6 = a[6], r7 = a[7];
        int lim = n - (n % 8);
        int i = 8;
        for (; i < lim; i += 8) {
            r0 += a[i + 0]; r1 += a[i + 1]; r2 += a[i + 2]; r3 += a[i + 3];
            r4 += a[i + 4]; r5 += a[i + 5]; r6 += a[i + 6]; r7 += a[i + 7];
        }
        float res = ((r0 + r1) + (r2 + r3)) + ((r4 + r5) + (r6 + r7));
        for (; i < n; ++i) res += a[i];
        val[id] = res;
    }
    __syncthreads();
    for (int l = 1; l <= PW.maxLvl; ++l) {
        for (int id = tid; id < PW.nNode; id += 256)
            if (PW.kind[id] == 1 && PW.lvl[id] == l)
                val[id] = val[PW.li[id]] + val[PW.ri[id]];
        __syncthreads();
    }
    if (tid == 0) {
        float io1 = depth[0];
        for (int r = 0; r < PW.nRoots; ++r)
            io1 = io1 + val[PW.roots[r]];
        meanp[0] = io1 / 65025.0f;
    }
}

// ---------------- prep: u2H fields + DFT W + padded bf16 image --------------
__global__ void k_prep(const float* __restrict__ img, unsigned short* __restrict__ IMG2,
                       float2* __restrict__ W,
                       float2* __restrict__ U2, float2* __restrict__ Hb,
                       const float* __restrict__ meanp,
                       double xstart, double xstep, double xstop,
                       double fstart, double fstep, double fstop,
                       float ap_f) {
#pragma clang fp contract(off)
    int idx = blockIdx.x * 256 + threadIdx.x;
    if (idx < 3 * NP) {
        int c = idx / NP, ij = idx % NP, i = ij / M, j = ij % M;
        const float wls[3] = {6.1e-07f, 5.3e-07f, 4.7e-07f};
        float wl = wls[c];
        float ki = ((float)6.283185307179586) / wl;
        float d  = meanp[0];
        float d2 = d * d;

        float x  = (i == 254) ? (float)xstop : (float)((double)i * xstep + xstart);
        float y  = (j == 254) ? (float)xstop : (float)((double)j * xstep + xstart);
        float fx = (i == 254) ? (float)fstop : (float)((double)i * fstep + fstart);
        float fy = (j == 254) ? (float)fstop : (float)((double)j * fstep + fstart);

        float xx = x * x, yy = y * y;
        float X1Y1 = xx + yy;

        float s  = sqrtf(X1Y1 + d2);
        float th = ki * s;
        float A  = (sqrtf(X1Y1) / ap_f <= 1.0f) ? 1.0f : 0.0f;
        float2 u2v;
        if (A != 0.0f) u2v = make_float2((float)cos((double)th), (float)sin((double)th));
        else           u2v = make_float2(0.0f, 0.0f);

        float a = wl * fx, b = wl * fy;
        float arg = (1.0f - a * a) - b * b;
        float FXY = sqrtf(fmaxf(arg, 0.0f));
        float Hv  = (sqrtf(fx * fx + fy * fy) < (1.0f / wl)) ? 1.0f : 0.0f;
        float kd  = ki * d;
        float ph  = kd * FXY;
        float cph = (float)cos((double)ph), sph = (float)sin((double)ph);
        float2 hv = make_float2(Hv * cph, Hv * sph);

        U2[idx] = u2v;
        Hb[idx] = hv;
        return;
    }
    if (idx < 4 * NP) {
        int e = idx - 3 * NP;
        int n = e / M, k = e % M;
        int m = (n * k) % M;
        double ang = -2.0 * 3.14159265358979323846 * (double)m / 255.0;
        W[e] = make_float2((float)cos(ang), (float)sin(ang));
        return;
    }
    int e = idx - 4 * NP;
    if (e >= IMG_SIDE) return;
    int ch = e / IMG_CH, rem = e % IMG_CH;
    int prow = rem / IMG_COLS, pcol = rem % IMG_COLS;
    int a = prow - 80, b = pcol - 80;
    float v = 0.0f;
    if (a >= 0 && a < M && b >= 0 && b < M) v = img[(a * M + b) * 3 + ch];
    unsigned short hi = f2bf(v);
    unsigned short lo = f2bf(v - bf2f(hi));
    IMG2[e] = hi;
    IMG2[IMG_SIDE + e] = lo;
}

// ---------------- batched f32 complex GEMM, 32x32 tile, 2x2/thread ----------
__global__ __launch_bounds__(256)
void k_cgemm(const float2* __restrict__ A, int aBatch,
             const float2* __restrict__ B, const float2* __restrict__ B2,
             int bBatch, float2* __restrict__ C,
             int conjA, int conjB, float scale) {
    __shared__ float2 As[32][17];
    __shared__ float2 Bs[16][33];
    int c = blockIdx.z;
    int tx = threadIdx.x & 15, ty = threadIdx.x >> 4;
    int i0 = blockIdx.y * 32, j0 = blockIdx.x * 32;
    const float2* Ab = A + (size_t)c * aBatch;
    const float2* Bb = B + (size_t)c * bBatch;
    const float2* B2b = B2 ? (B2 + (size_t)c * bBatch) : nullptr;
    float2 a00 = {0,0}, a01 = {0,0}, a10 = {0,0}, a11 = {0,0};

    for (int kt = 0; kt < 16; ++kt) {
        int k0 = kt * 16;
#pragma unroll
        for (int s = 0; s < 2; ++s) {
            int idx = threadIdx.x + s * 256;
            int r = idx >> 4, cc = idx & 15;
            int gi = i0 + r, gk = k0 + cc;
            float2 v = (gi < M && gk < M) ? Ab[gi * M + gk] : make_float2(0.f, 0.f);
            if (conjA) v.y = -v.y;
            As[r][cc] = v;
            int r2 = idx >> 5, c2 = idx & 31;
            int gk2 = k0 + r2, gj = j0 + c2;
            float2 w = make_float2(0.f, 0.f);
            if (gk2 < M && gj < M) {
                w = Bb[gk2 * M + gj];
                if (B2b) {
                    float2 z = B2b[gk2 * M + gj];
                    w = make_float2(w.x * z.x - w.y * z.y, w.x * z.y + w.y * z.x);
                }
            }
            if (conjB) w.y = -w.y;
            Bs[r2][c2] = w;
        }
        __syncthreads();
#pragma unroll
        for (int kk = 0; kk < 16; ++kk) {
            float2 p = As[ty][kk], q = As[ty + 16][kk];
            float2 u = Bs[kk][tx], v = Bs[kk][tx + 16];
            a00.x += p.x * u.x - p.y * u.y;  a00.y += p.x * u.y + p.y * u.x;
            a01.x += p.x * v.x - p.y * v.y;  a01.y += p.x * v.y + p.y * v.x;
            a10.x += q.x * u.x - q.y * u.y;  a10.y += q.x * u.y + q.y * u.x;
            a11.x += q.x * v.x - q.y * v.y;  a11.y += q.x * v.y + q.y * v.x;
        }
        __syncthreads();
    }
    float2* Cb = C + (size_t)c * NP;
    int gi0 = i0 + ty, gi1 = i0 + ty + 16;
    int gj0 = j0 + tx, gj1 = j0 + tx + 16;
    if (gi0 < M && gj0 < M) Cb[gi0 * M + gj0] = make_float2(a00.x * scale, a00.y * scale);
    if (gi0 < M && gj1 < M) Cb[gi0 * M + gj1] = make_float2(a01.x * scale, a01.y * scale);
    if (gi1 < M && gj0 < M) Cb[gi1 * M + gj0] = make_float2(a10.x * scale, a10.y * scale);
    if (gi1 < M && gj1 < M) Cb[gi1 * M + gj1] = make_float2(a11.x * scale, a11.y * scale);
}

// ---------------- S = sum u3^2 (f64 accumulate over f32 u3) ----------------
__global__ void k_sred(const float2* __restrict__ U3, double2* __restrict__ spart) {
    __shared__ double sx[256], sy[256];
    int t = threadIdx.x;
    double ax = 0.0, ay = 0.0;
    for (int i = blockIdx.x * 256 + t; i < 3 * NP; i += 64 * 256) {
        double zx = (double)U3[i].x, zy = (double)U3[i].y;
        ax += zx * zx - zy * zy;
        ay += 2.0 * zx * zy;
    }
    sx[t] = ax; sy[t] = ay;
    __syncthreads();
    for (int w = 128; w > 0; w >>= 1) {
        if (t < w) { sx[t] += sx[t + w]; sy[t] += sy[t + w]; }
        __syncthreads();
    }
    if (t == 0) spart[blockIdx.x] = make_double2(sx[0], sy[0]);
}

// ---------------- psf -> P4 (4-shift-copy bf16 hi/lo band table) ------------
__global__ void k_p4(const float2* __restrict__ U3, const double2* __restrict__ spart,
                     unsigned short* __restrict__ P4) {
    int idx = blockIdx.x * 256 + threadIdx.x;
    if (idx >= P4_SIDE) return;
    double rx = 0.0, ry = 0.0;
    for (int i = 0; i < 64; ++i) { rx += spart[i].x; ry += spart[i].y; }
    double dsx = rx + 1e-7, dsy = ry;            // same association as before
    int ch = idx / P4_CH, rem = idx % P4_CH;
    int di = rem / P4_DI, rem2 = rem % P4_DI;
    int r = rem2 / 320, e = rem2 % 320;
    int u = e - 16 + r;
    float v = 0.0f;
    if (di < M && u >= 0 && u < M) {
        double inv = 1.0 / (dsx * dsx + dsy * dsy);
        float2 zf = U3[(ch * M + di) * M + u];
        double zx = (double)zf.x, zy = (double)zf.y;
        double zr = zx * zx - zy * zy;
        double zi = 2.0 * zx * zy;
        v = (float)((zr * dsx + zi * dsy) * inv);
    }
    unsigned short hi = f2bf(v);
    unsigned short lo = f2bf(v - bf2f(hi));
    P4[idx] = hi;
    P4[P4_SIDE + idx] = lo;
}

// ---------------- MFMA conv: banded-Toeplitz implicit GEMM ------------------
// wave = one 16x16 output tile (i0..i0+15 x j0..j0+15), one (ch, di-chunk).
// C[m][n] += sum_k A[m][k] * B[k][n];  A = psf band, B = img rows.
// A[m=lane&15][k=8q+t] = psf[di][32c + 8q + t - m]   (from P4 shifted copies)
// B[k=8q+t][n=lane&15] = img[i0+n+di-80][j0-80+32c+8q+t]  (from IMG2 padded)
// D: row(=m/j) = 4q+reg, col(=n/i) = lane&15.
__global__ __launch_bounds__(64)
void k_conv(const unsigned short* __restrict__ IMG2,
            const unsigned short* __restrict__ P4,
            float* __restrict__ PART) {
    int lane = threadIdx.x;
    int ln = lane & 15;            // m for A, n for B/C-col
    int q  = lane >> 4;            // 0..3
    int j0 = blockIdx.x * 16;
    int i0 = blockIdx.y * 16;
    int bz = blockIdx.z;           // ch*16 + chunk
    int ch = bz >> 4, chunk = bz & 15;
    int d0 = chunk << 4;

    const unsigned short* imgH = IMG2 + ch * IMG_CH;
    const unsigned short* imgL = imgH + IMG_SIDE;
    const unsigned short* pHc  = P4 + ch * P4_CH;
    const unsigned short* pLc  = pHc + P4_SIDE;

    f32x4 acc = {0.f, 0.f, 0.f, 0.f};

    for (int dd = 0; dd < 16; ++dd) {
        int di = d0 + dd;
        const unsigned short* prH = pHc + di * P4_DI;
        const unsigned short* prL = pLc + di * P4_DI;
        int irow = i0 + ln + di;               // padded row index
        const unsigned short* brH = imgH + irow * IMG_COLS;
        const unsigned short* brL = imgL + irow * IMG_COLS;
#pragma unroll
        for (int cc = 0; cc < 9; ++cc) {
            int s  = 32 * cc + 8 * q - ln;     // A band start (dj space)
            int su = s + 16;
            int r  = su & 3;
            int e  = su - r;
            const unsigned short* pa = prH + r * 320 + e;
            const unsigned short* pl = prL + r * 320 + e;
            ushort4 a0 = *(const ushort4*)(pa);
            ushort4 a1 = *(const ushort4*)(pa + 4);
            ushort4 l0 = *(const ushort4*)(pl);
            ushort4 l1 = *(const ushort4*)(pl + 4);
            int pcol = j0 + 32 * cc + 8 * q;   // padded col (16B aligned)
            short8 bh = *(const short8*)(brH + pcol);
            short8 bl = *(const short8*)(brL + pcol);
            short8 ah, al;
            ah[0] = (short)a0.x; ah[1] = (short)a0.y; ah[2] = (short)a0.z; ah[3] = (short)a0.w;
            ah[4] = (short)a1.x; ah[5] = (short)a1.y; ah[6] = (short)a1.z; ah[7] = (short)a1.w;
            al[0] = (short)l0.x; al[1] = (short)l0.y; al[2] = (short)l0.z; al[3] = (short)l0.w;
            al[4] = (short)l1.x; al[5] = (short)l1.y; al[6] = (short)l1.z; al[7] = (short)l1.w;
            acc = __builtin_amdgcn_mfma_f32_16x16x32_bf16(ah, bh, acc, 0, 0, 0);
            acc = __builtin_amdgcn_mfma_f32_16x16x32_bf16(ah, bl, acc, 0, 0, 0);
            acc = __builtin_amdgcn_mfma_f32_16x16x32_bf16(al, bh, acc, 0, 0, 0);
        }
    }

    // D row = 4q+reg -> j = j0+4q+reg ; D col = ln -> i = i0+ln
    float* op = PART + (size_t)bz * (RESO * RESO) + (i0 + ln) * RESO + j0 + 4 * q;
    float4 o; o.x = acc[0]; o.y = acc[1]; o.z = acc[2]; o.w = acc[3];
    *(float4*)op = o;
}

// ---------------- reduce partials + clip + layout (i,j,c) ----------------
__global__ void k_out(const float* __restrict__ PART, float* __restrict__ out) {
    int idx = blockIdx.x * 256 + threadIdx.x;
    if (idx >= 3 * RESO * RESO) return;
    int c = idx / (RESO * RESO), ij = idx % (RESO * RESO);
    float s = 0.0f;
    for (int kz = 0; kz < 16; ++kz)
        s += PART[(size_t)(c * 16 + kz) * (RESO * RESO) + ij];
    s = fminf(fmaxf(s, 0.0f), 1.0f);
    int i = ij / RESO, j = ij % RESO;
    out[(i * RESO + j) * 3 + c] = s;
}

// ---------------------------------------------------------------------------
extern "C" void kernel_launch(void* const* d_in, const int* in_sizes, int n_in,
                              void* d_out, int out_size, void* d_ws, size_t ws_size,
                              hipStream_t stream) {
    const float* image = (const float*)d_in[0];   // (255,255,3)
    const float* depth = (const float*)d_in[1];   // (255,255)
    float* out = (float*)d_out;                   // (160,160,3)

    // workspace carve (256B aligned), ~22.5 MB
    char* p = (char*)d_ws;
    auto alloc = [&](size_t bytes) { void* r = (void*)p; p += (bytes + 255) & ~(size_t)255; return r; };
    float*   meanp = (float*)alloc(4);
    float2*  Wf    = (float2*)alloc((size_t)NP * 8);
    float2*  UH    = (float2*)alloc((size_t)6 * NP * 8);   // U2 | Hb
    float2*  Td    = (float2*)alloc((size_t)6 * NP * 8);
    float2*  EF    = (float2*)alloc((size_t)6 * NP * 8);   // FU | FH
    float2*  U3    = (float2*)alloc((size_t)3 * NP * 8);
    double2* spart = (double2*)alloc(64 * 16);
    unsigned short* P4   = (unsigned short*)alloc((size_t)2 * P4_SIDE * 2);
    unsigned short* IMG2 = (unsigned short*)alloc((size_t)2 * IMG_SIDE * 2);
    float*   PART  = (float*)alloc((size_t)48 * RESO * RESO * 4);

    float2* U2 = UH;
    float2* Hb = UH + (size_t)3 * NP;

    // exact python-f64 scalar path
    double dx = 0.002 / 255.0;
    double Lx = dx * 255.0;
    double ap = (Lx / 2.0) * 0.1 + 1e-7;
    float ap_f = (float)ap;

    double xstart = -(Lx / 2.0);
    double xstop  =  Lx / 2.0;
    double xstep  = (xstop - xstart) / 254.0;
    double fstart = -1.0 / (2.0 * dx);
    double fstop  =  1.0 / (2.0 * dx);
    double fstep  = (fstop - fstart) / 254.0;

    k_mean<<<1, 256, 0, stream>>>(depth, meanp);
    int gprep = (4 * NP + IMG_SIDE + 255) / 256;   // 3201
    k_prep<<<gprep, 256, 0, stream>>>(image, IMG2, Wf, U2, Hb, meanp,
                                      xstart, xstep, xstop,
                                      fstart, fstep, fstop, ap_f);

    dim3 bb(256);
    k_cgemm<<<dim3(8, 8, 6), bb, 0, stream>>>(Wf, 0, UH, nullptr, NP, Td, 0, 0, 1.0f);
    k_cgemm<<<dim3(8, 8, 6), bb, 0, stream>>>(Td, NP, Wf, nullptr, 0, EF, 0, 0, 1.0f);
    k_cgemm<<<dim3(8, 8, 3), bb, 0, stream>>>(Wf, 0, EF + (size_t)3 * NP, EF, NP,
                                              Td, 1, 0, 1.0f / 255.0f);
    k_cgemm<<<dim3(8, 8, 3), bb, 0, stream>>>(Td, NP, Wf, nullptr, 0, U3, 0, 1,
                                              1.0f / 255.0f);

    k_sred<<<64, 256, 0, stream>>>(U3, spart);
    k_p4<<<(P4_SIDE + 255) / 256, 256, 0, stream>>>(U3, spart, P4);

    k_conv<<<dim3(10, 10, 48), 64, 0, stream>>>(IMG2, P4, PART);
    k_out<<<300, 256, 0, stream>>>(PART, out);
}